// Round 1
// baseline (414.949 us; speedup 1.0000x reference)
//
#include <hip/hip_runtime.h>
#include <hip/hip_bf16.h>

#define LN_EPS 1e-5f

// ---------- helpers ----------
__device__ __forceinline__ float wred_sum(float v) {
#pragma unroll
  for (int o = 32; o > 0; o >>= 1) v += __shfl_xor(v, o, 64);
  return v;
}
__device__ __forceinline__ float wred_max(float v) {
#pragma unroll
  for (int o = 32; o > 0; o >>= 1) v = fmaxf(v, __shfl_xor(v, o, 64));
  return v;
}
// block (256 thr) sum; result broadcast to all threads
__device__ __forceinline__ float bsum256(float v, float* s4) {
  v = wred_sum(v);
  int lane = threadIdx.x & 63, w = threadIdx.x >> 6;
  __syncthreads();
  if (lane == 0) s4[w] = v;
  __syncthreads();
  return s4[0] + s4[1] + s4[2] + s4[3];
}

// ---------- LN of wpe rows (wave per row, D=256) ----------
__global__ void ln_wpe_k(const float* __restrict__ wpe, const float* __restrict__ g,
                         float* __restrict__ p0) {
  int w = threadIdx.x >> 6, lane = threadIdx.x & 63;
  int row = blockIdx.x * 4 + w;  // 0..4095
  const float4* src = (const float4*)(wpe + (size_t)row * 256);
  float4 v = src[lane];
  float mean = wred_sum(v.x + v.y + v.z + v.w) * (1.f / 256.f);
  float4 d = {v.x - mean, v.y - mean, v.z - mean, v.w - mean};
  float var = wred_sum(d.x * d.x + d.y * d.y + d.z * d.z + d.w * d.w) * (1.f / 256.f);
  float r = rsqrtf(var + LN_EPS);
  float4 gv = ((const float4*)g)[lane];
  float4 o = {d.x * r * gv.x, d.y * r * gv.y, d.z * r * gv.z, d.w * r * gv.w};
  ((float4*)(p0 + (size_t)row * 256))[lane] = o;
}

// ---------- e = LN(wte[tokens], g_e) (wave per row) ----------
__global__ void ln_e_k(const float* __restrict__ wte, const int* __restrict__ tokens,
                       const float* __restrict__ g, float* __restrict__ e) {
  int w = threadIdx.x >> 6, lane = threadIdx.x & 63;
  int row = blockIdx.x * 4 + w;  // 0..16383 (= b*4096+s)
  int tok = tokens[row];
  const float4* src = (const float4*)(wte + (size_t)tok * 256);
  float4 v = src[lane];
  float mean = wred_sum(v.x + v.y + v.z + v.w) * (1.f / 256.f);
  float4 d = {v.x - mean, v.y - mean, v.z - mean, v.w - mean};
  float var = wred_sum(d.x * d.x + d.y * d.y + d.z * d.z + d.w * d.w) * (1.f / 256.f);
  float r = rsqrtf(var + LN_EPS);
  float4 gv = ((const float4*)g)[lane];
  float4 o = {d.x * r * gv.x, d.y * r * gv.y, d.z * r * gv.z, d.w * r * gv.w};
  ((float4*)(e + (size_t)row * 256))[lane] = o;
}

// ---------- 64x64-tile transpose: in (M x N) -> out (N x M) ----------
__global__ void transpose_k(const float* __restrict__ in, float* __restrict__ out,
                            int M, int N) {
  __shared__ float lds[64][65];
  int t = threadIdx.x;
  int x = t & 63, y4 = t >> 6;
  int r0 = blockIdx.x * 64, c0 = blockIdx.y * 64;
#pragma unroll
  for (int i = 0; i < 16; ++i) {
    int r = y4 * 16 + i;
    lds[r][x] = in[(size_t)(r0 + r) * N + c0 + x];
  }
  __syncthreads();
#pragma unroll
  for (int i = 0; i < 16; ++i) {
    int a = y4 * 16 + i;
    out[(size_t)(c0 + a) * M + r0 + x] = lds[x][a];
  }
}

// ---------- generic transposed-layout GEMM ----------
// CT[n][m] = epilogue( sum_k AT[k*M+m] * B[k*N+n] )
// mode 0: none;  mode 1: exact gelu;  mode 2: += resT[n*M+m]
// blockIdx.z selects layer: B += z*K*N, CT += z*N*M
__global__ void gemm_t(const float* __restrict__ AT, const float* __restrict__ B,
                       float* __restrict__ CT, const float* __restrict__ resT,
                       float* __restrict__ lastrow,
                       int M, int N, int K, int mode) {
  int m = blockIdx.x * 256 + threadIdx.x;
  int n0 = blockIdx.y * 16;
  const float* Bl = B + (size_t)blockIdx.z * K * N;
  float* Cl = CT + (size_t)blockIdx.z * N * M;
  float acc[16];
#pragma unroll
  for (int i = 0; i < 16; ++i) acc[i] = 0.f;
#pragma unroll 8
  for (int k = 0; k < K; ++k) {
    float a = AT[(size_t)k * M + m];
    const float* brow = Bl + (size_t)k * N + n0;  // wave-uniform -> s_load
#pragma unroll
    for (int i = 0; i < 16; ++i) acc[i] += a * brow[i];
  }
#pragma unroll
  for (int i = 0; i < 16; ++i) {
    float v = acc[i];
    if (mode == 1) v = 0.5f * v * (1.f + erff(v * 0.70710678118654752f));
    if (mode == 2) v += resT[(size_t)(n0 + i) * M + m];
    Cl[(size_t)(n0 + i) * M + m] = v;
    if (lastrow && m == M - 1) lastrow[n0 + i] = v;
  }
}

// ---------- q at last position for all 6 layers ----------
__global__ void qlast_k(const float* __restrict__ plast, const float* __restrict__ Wq,
                        float* __restrict__ qall) {
  int l = blockIdx.x, t = threadIdx.x;
  const float* W = Wq + (size_t)l * 65536;
  float acc = 0.f;
#pragma unroll 8
  for (int d = 0; d < 256; ++d) acc += plast[d] * W[d * 256 + t];  // plast: s_load
  qall[l * 256 + t] = acc;
}

// ---------- scores sc[l][t] = q_l . k_l[t] / 16 ----------
__global__ void scores_k(const float* __restrict__ kT, const float* __restrict__ qall,
                         float* __restrict__ sc) {
  int l = blockIdx.y;
  int t = blockIdx.x * 256 + threadIdx.x;
  const float* kTl = kT + (size_t)l * 256 * 4096;
  const float* q = qall + l * 256;
  float acc = 0.f;
#pragma unroll 8
  for (int c = 0; c < 256; ++c) acc += q[c] * kTl[(size_t)c * 4096 + t];
  sc[l * 4096 + t] = acc * 0.0625f;  // 1/sqrt(256)
}

// ---------- softmax over 4096 per layer (one block per layer) ----------
__global__ void softmax_k(const float* __restrict__ sc, float* __restrict__ w) {
  int l = blockIdx.x, t = threadIdx.x;  // 1024 threads, 4 elems each
  float4 v = ((const float4*)(sc + (size_t)l * 4096))[t];
  float m = fmaxf(fmaxf(v.x, v.y), fmaxf(v.z, v.w));
  m = wred_max(m);
  __shared__ float red[16];
  __shared__ float red2[16];
  int lane = t & 63, wv = t >> 6;
  if (lane == 0) red[wv] = m;
  __syncthreads();
  float mm = red[0];
#pragma unroll
  for (int i = 1; i < 16; ++i) mm = fmaxf(mm, red[i]);
  float e0 = expf(v.x - mm), e1 = expf(v.y - mm), e2 = expf(v.z - mm), e3 = expf(v.w - mm);
  float s = wred_sum(e0 + e1 + e2 + e3);
  if (lane == 0) red2[wv] = s;
  __syncthreads();
  float tot = 0.f;
#pragma unroll
  for (int i = 0; i < 16; ++i) tot += red2[i];
  float inv = 1.f / tot;
  float4 o = {e0 * inv, e1 * inv, e2 * inv, e3 * inv};
  ((float4*)(w + (size_t)l * 4096))[t] = o;
}

// ---------- ctx[l][b][d] = sum_t w[l][t]*e[b][t][d] (split over t-chunks) ----------
__global__ void ctx_k(const float* __restrict__ e, const float* __restrict__ w,
                      float* __restrict__ ctx) {
  int c = blockIdx.x, b = blockIdx.y, l = blockIdx.z;
  int d = threadIdx.x;
  const float* wl = w + (size_t)l * 4096 + c * 256;          // wave-uniform
  const float* eb = e + ((size_t)b * 4096 + c * 256) * 256;  // coalesced over d
  float acc = 0.f;
#pragma unroll 4
  for (int i = 0; i < 256; ++i) acc += wl[i] * eb[(size_t)i * 256 + d];
  atomicAdd(&ctx[(l * 4 + b) * 256 + d], acc);
}

// ---------- out_all[l][b] = ctx[l][b] @ Wv[l] ----------
__global__ void proj_k(const float* __restrict__ ctx, const float* __restrict__ Wv,
                       float* __restrict__ outall) {
  int b = blockIdx.x, l = blockIdx.y, t = threadIdx.x;
  const float* cl = ctx + (l * 4 + b) * 256;  // wave-uniform
  const float* W = Wv + (size_t)l * 65536;
  float acc = 0.f;
#pragma unroll 8
  for (int d = 0; d < 256; ++d) acc += cl[d] * W[d * 256 + t];
  outall[(l * 4 + b) * 256 + t] = acc;
}

// ---------- xln[b] = LN(e[b,4095]+p0[4095]+sum_l out_all[l][b], g_out) ----------
__global__ void final_k(const float* __restrict__ e, const float* __restrict__ p0,
                        const float* __restrict__ outall, const float* __restrict__ gout,
                        float* __restrict__ xln) {
  int b = blockIdx.x, t = threadIdx.x;
  float v = e[((size_t)(b * 4096 + 4095)) * 256 + t] + p0[(size_t)4095 * 256 + t];
#pragma unroll
  for (int l = 0; l < 6; ++l) v += outall[(l * 4 + b) * 256 + t];
  __shared__ float s4[4];
  float mean = bsum256(v, s4) * (1.f / 256.f);
  float d = v - mean;
  float var = bsum256(d * d, s4) * (1.f / 256.f);
  xln[b * 256 + t] = d * rsqrtf(var + LN_EPS) * gout[t];
}

// ---------- logits[b][v] = xln[b] . LN(wte[v], g_e)  (wave per vocab row) ----------
__global__ void logits_k(const float* __restrict__ wte, const float* __restrict__ ge,
                         const float* __restrict__ xln, float* __restrict__ out) {
  int wv = threadIdx.x >> 6, lane = threadIdx.x & 63;
  int v = blockIdx.x * 4 + wv;  // 0..31999
  float4 x = ((const float4*)(wte + (size_t)v * 256))[lane];
  float mean = wred_sum(x.x + x.y + x.z + x.w) * (1.f / 256.f);
  float4 d = {x.x - mean, x.y - mean, x.z - mean, x.w - mean};
  float var = wred_sum(d.x * d.x + d.y * d.y + d.z * d.z + d.w * d.w) * (1.f / 256.f);
  float r = rsqrtf(var + LN_EPS);
  float4 gv = ((const float4*)ge)[lane];
  float4 ln = {d.x * r * gv.x, d.y * r * gv.y, d.z * r * gv.z, d.w * r * gv.w};
#pragma unroll
  for (int b = 0; b < 4; ++b) {
    float4 xv = ((const float4*)(xln + b * 256))[lane];
    float dot = wred_sum(ln.x * xv.x + ln.y * xv.y + ln.z * xv.z + ln.w * xv.w);
    if (lane == 0) out[b * 32000 + v] = dot;
  }
}

// ---------- workspace layout (floats) ----------
#define O_P0   ((size_t)0)          // 4096*256
#define O_P0T  ((size_t)1048576)    // 256*4096
#define O_HT   ((size_t)2097152)    // 1024*4096
#define O_PT   ((size_t)6291456)    // 256*4096
#define O_PLAST ((size_t)7340032)   // 256
#define O_QALL ((size_t)7340288)    // 6*256
#define O_KT   ((size_t)7341824)    // 6*256*4096
#define O_E    ((size_t)13633280)   // 16384*256
#define O_SC   ((size_t)17827584)   // 6*4096
#define O_WSM  ((size_t)17852160)   // 6*4096
#define O_CTX  ((size_t)17876736)   // 6*4*256
#define O_OUTA ((size_t)17882880)   // 6*4*256
#define O_XLN  ((size_t)17889024)   // 4*256

extern "C" void kernel_launch(void* const* d_in, const int* in_sizes, int n_in,
                              void* d_out, int out_size, void* d_ws, size_t ws_size,
                              hipStream_t stream) {
  const int*   tokens = (const int*)d_in[0];
  const float* wte    = (const float*)d_in[1];
  const float* wpe    = (const float*)d_in[2];
  const float* g_e    = (const float*)d_in[3];
  const float* g_p    = (const float*)d_in[4];
  const float* g_out  = (const float*)d_in[5];
  const float* ff_w1  = (const float*)d_in[6];
  const float* ff_w2  = (const float*)d_in[7];
  const float* Wq     = (const float*)d_in[8];
  const float* Wk     = (const float*)d_in[9];
  const float* Wv     = (const float*)d_in[10];
  float* out = (float*)d_out;
  float* ws = (float*)d_ws;

  float* p0   = ws + O_P0;
  float* p0T  = ws + O_P0T;
  float* hT   = ws + O_HT;
  float* pT   = ws + O_PT;
  float* plast= ws + O_PLAST;
  float* qall = ws + O_QALL;
  float* kT   = ws + O_KT;
  float* e    = ws + O_E;
  float* sc   = ws + O_SC;
  float* wsm  = ws + O_WSM;
  float* ctx  = ws + O_CTX;
  float* outa = ws + O_OUTA;
  float* xln  = ws + O_XLN;

  // 1. p0 = LN(wpe[:4096], g_p)
  ln_wpe_k<<<1024, 256, 0, stream>>>(wpe, g_p, p0);
  // 2. e = LN(wte[tokens], g_e)
  ln_e_k<<<4096, 256, 0, stream>>>(wte, tokens, g_e, e);
  // 3. p0T = p0^T
  transpose_k<<<dim3(64, 4), 256, 0, stream>>>(p0, p0T, 4096, 256);
  // 4. hT = gelu(p0 @ ff_w1)^T
  gemm_t<<<dim3(16, 64, 1), 256, 0, stream>>>(p0T, ff_w1, hT, nullptr, nullptr,
                                              4096, 1024, 256, 1);
  // 5. pT = (p0 + h @ ff_w2)^T ; also extract p[4095]
  gemm_t<<<dim3(16, 16, 1), 256, 0, stream>>>(hT, ff_w2, pT, p0T, plast,
                                              4096, 256, 1024, 2);
  // 6. q_last for all layers
  qlast_k<<<6, 256, 0, stream>>>(plast, Wq, qall);
  // 7. kT[l] = (p @ Wk[l])^T for all layers
  gemm_t<<<dim3(16, 16, 6), 256, 0, stream>>>(pT, Wk, kT, nullptr, nullptr,
                                              4096, 256, 256, 0);
  // 8. scores
  scores_k<<<dim3(16, 6), 256, 0, stream>>>(kT, qall, sc);
  // 9. softmax
  softmax_k<<<6, 1024, 0, stream>>>(sc, wsm);
  // 10. ctx accum (zero first)
  hipMemsetAsync(ctx, 0, 6 * 4 * 256 * sizeof(float), stream);
  ctx_k<<<dim3(16, 4, 6), 256, 0, stream>>>(e, wsm, ctx);
  // 11. project ctx through Wv
  proj_k<<<dim3(4, 6), 256, 0, stream>>>(ctx, Wv, outa);
  // 12. final LN at last position
  final_k<<<4, 256, 0, stream>>>(e, p0, outa, g_out, xln);
  // 13. logits
  logits_k<<<8000, 256, 0, stream>>>(wte, g_e, xln, out);
}

// Round 2
// 236.446 us; speedup vs baseline: 1.7549x; 1.7549x over previous
//
#include <hip/hip_runtime.h>
#include <hip/hip_bf16.h>

#define LN_EPS 1e-5f

typedef __attribute__((ext_vector_type(8))) short s8v;
typedef __attribute__((ext_vector_type(4))) float f32x4;

// ---------- helpers ----------
__device__ __forceinline__ float wred_sum(float v) {
#pragma unroll
  for (int o = 32; o > 0; o >>= 1) v += __shfl_xor(v, o, 64);
  return v;
}
__device__ __forceinline__ float wred_max(float v) {
#pragma unroll
  for (int o = 32; o > 0; o >>= 1) v = fmaxf(v, __shfl_xor(v, o, 64));
  return v;
}
__device__ __forceinline__ float bsum256(float v, float* s4) {
  v = wred_sum(v);
  int lane = threadIdx.x & 63, w = threadIdx.x >> 6;
  __syncthreads();
  if (lane == 0) s4[w] = v;
  __syncthreads();
  return s4[0] + s4[1] + s4[2] + s4[3];
}
__device__ __forceinline__ float bf2f(unsigned short u) {
  union { unsigned int i; float f; } c;
  c.i = ((unsigned int)u) << 16;
  return c.f;
}

// ---------- LN(wpe) -> p0 f32 + p0 bf16 ----------
__global__ void ln_wpe_k(const float* __restrict__ wpe, const float* __restrict__ g,
                         float* __restrict__ p0, __hip_bfloat16* __restrict__ p0b) {
  int w = threadIdx.x >> 6, lane = threadIdx.x & 63;
  int row = blockIdx.x * 4 + w;
  const float4* src = (const float4*)(wpe + (size_t)row * 256);
  float4 v = src[lane];
  float mean = wred_sum(v.x + v.y + v.z + v.w) * (1.f / 256.f);
  float4 d = {v.x - mean, v.y - mean, v.z - mean, v.w - mean};
  float var = wred_sum(d.x * d.x + d.y * d.y + d.z * d.z + d.w * d.w) * (1.f / 256.f);
  float r = rsqrtf(var + LN_EPS);
  float4 gv = ((const float4*)g)[lane];
  float4 o = {d.x * r * gv.x, d.y * r * gv.y, d.z * r * gv.z, d.w * r * gv.w};
  ((float4*)(p0 + (size_t)row * 256))[lane] = o;
  __hip_bfloat16* ob = p0b + (size_t)row * 256 + lane * 4;
  ob[0] = (__hip_bfloat16)o.x; ob[1] = (__hip_bfloat16)o.y;
  ob[2] = (__hip_bfloat16)o.z; ob[3] = (__hip_bfloat16)o.w;
}

// ---------- e = LN(wte[tokens], g_e) f32 ----------
__global__ void ln_e_k(const float* __restrict__ wte, const int* __restrict__ tokens,
                       const float* __restrict__ g, float* __restrict__ e) {
  int w = threadIdx.x >> 6, lane = threadIdx.x & 63;
  int row = blockIdx.x * 4 + w;
  int tok = tokens[row];
  const float4* src = (const float4*)(wte + (size_t)tok * 256);
  float4 v = src[lane];
  float mean = wred_sum(v.x + v.y + v.z + v.w) * (1.f / 256.f);
  float4 d = {v.x - mean, v.y - mean, v.z - mean, v.w - mean};
  float var = wred_sum(d.x * d.x + d.y * d.y + d.z * d.z + d.w * d.w) * (1.f / 256.f);
  float r = rsqrtf(var + LN_EPS);
  float4 gv = ((const float4*)g)[lane];
  float4 o = {d.x * r * gv.x, d.y * r * gv.y, d.z * r * gv.z, d.w * r * gv.w};
  ((float4*)(e + (size_t)row * 256))[lane] = o;
}

// ---------- transpose + cast f32 -> bf16 : out[n*M+m] = in[m*N+n] ----------
__global__ void tcast_k(const float* __restrict__ in, __hip_bfloat16* __restrict__ out,
                        int M, int N) {
  __shared__ float lds[64][65];
  int t = threadIdx.x, x = t & 63, y4 = t >> 6;
  int r0 = blockIdx.x * 64, c0 = blockIdx.y * 64;
  const float* inz = in + (size_t)blockIdx.z * M * N;
  __hip_bfloat16* outz = out + (size_t)blockIdx.z * M * N;
#pragma unroll
  for (int i = 0; i < 16; ++i) {
    int r = y4 * 16 + i;
    lds[r][x] = inz[(size_t)(r0 + r) * N + c0 + x];
  }
  __syncthreads();
#pragma unroll
  for (int i = 0; i < 16; ++i) {
    int a = y4 * 16 + i;
    outz[(size_t)(c0 + a) * M + r0 + x] = (__hip_bfloat16)lds[x][a];
  }
}

// ---------- MFMA GEMM: C(MxN) = A(MxK) @ B, B given as BT(NxK) ----------
// bf16 in, f32 acc, bf16 out. mode 0: none; 1: exact gelu; 2: += res(f32 MxN)
// blockIdx.z: BT += z*N*K, Cout += z*M*N
__global__ __launch_bounds__(256) void mfma_gemm(
    const __hip_bfloat16* __restrict__ A, const __hip_bfloat16* __restrict__ BT,
    __hip_bfloat16* __restrict__ Cout, const float* __restrict__ res,
    int M, int N, int K, int mode) {
  __shared__ __hip_bfloat16 As[128][40];
  __shared__ __hip_bfloat16 Bs[128][40];
  int t = threadIdx.x;
  int lane = t & 63, wave = t >> 6;
  int wr = wave >> 1, wc = wave & 1;            // 2x2 waves -> 64x64 each
  int m0 = blockIdx.x * 128, n0 = blockIdx.y * 128;
  const __hip_bfloat16* Bl = BT + (size_t)blockIdx.z * N * K;
  __hip_bfloat16* Cl = Cout + (size_t)blockIdx.z * M * N;

  f32x4 zero = {0.f, 0.f, 0.f, 0.f};
  f32x4 acc[4][4];
#pragma unroll
  for (int i = 0; i < 4; ++i)
#pragma unroll
    for (int j = 0; j < 4; ++j) acc[i][j] = zero;

  int srow = t >> 1, schunk = (t & 1) * 16;     // each thread stages 16 bf16 = 32B
  int quad = lane >> 4, fr = lane & 15;

  for (int k0 = 0; k0 < K; k0 += 32) {
    const float4* ga = (const float4*)(A + (size_t)(m0 + srow) * K + k0 + schunk);
    const float4* gb = (const float4*)(Bl + (size_t)(n0 + srow) * K + k0 + schunk);
    float4 av0 = ga[0], av1 = ga[1];
    float4 bv0 = gb[0], bv1 = gb[1];
    __syncthreads();
    *(float4*)&As[srow][schunk] = av0; *(float4*)&As[srow][schunk + 8] = av1;
    *(float4*)&Bs[srow][schunk] = bv0; *(float4*)&Bs[srow][schunk + 8] = bv1;
    __syncthreads();
    s8v af[4], bf[4];
#pragma unroll
    for (int i = 0; i < 4; ++i) {
      af[i] = *(const s8v*)&As[wr * 64 + i * 16 + fr][quad * 8];
      bf[i] = *(const s8v*)&Bs[wc * 64 + i * 16 + fr][quad * 8];
    }
#pragma unroll
    for (int i = 0; i < 4; ++i)
#pragma unroll
      for (int j = 0; j < 4; ++j)
        acc[i][j] = __builtin_amdgcn_mfma_f32_16x16x32_bf16(af[i], bf[j], acc[i][j], 0, 0, 0);
  }

#pragma unroll
  for (int i = 0; i < 4; ++i) {
#pragma unroll
    for (int j = 0; j < 4; ++j) {
#pragma unroll
      for (int r = 0; r < 4; ++r) {
        int row = m0 + wr * 64 + i * 16 + quad * 4 + r;
        int col = n0 + wc * 64 + j * 16 + fr;
        float v = acc[i][j][r];
        if (mode == 1) v = 0.5f * v * (1.f + erff(v * 0.70710678118654752f));
        if (mode == 2) v += res[(size_t)row * N + col];
        Cl[(size_t)row * N + col] = (__hip_bfloat16)v;
      }
    }
  }
}

// ---------- q at last position (p bf16) ----------
__global__ void qlast_k(const __hip_bfloat16* __restrict__ pB, const float* __restrict__ Wq,
                        float* __restrict__ qall) {
  int l = blockIdx.x, t = threadIdx.x;
  const __hip_bfloat16* plast = pB + (size_t)4095 * 256;
  const float* W = Wq + (size_t)l * 65536;
  float acc = 0.f;
#pragma unroll 8
  for (int d = 0; d < 256; ++d) acc += (float)plast[d] * W[d * 256 + t];
  qall[l * 256 + t] = acc;
}

// ---------- scores: wave per row, k bf16 ----------
__global__ void scores_k(const __hip_bfloat16* __restrict__ kB, const float* __restrict__ qall,
                         float* __restrict__ sc) {
  int w = threadIdx.x >> 6, lane = threadIdx.x & 63;
  int trow = blockIdx.x * 4 + w;
  int l = blockIdx.y;
  const unsigned short* kr = (const unsigned short*)(kB + ((size_t)l * 4096 + trow) * 256);
  ushort4 kv = ((const ushort4*)kr)[lane];
  float4 qv = ((const float4*)(qall + l * 256))[lane];
  float dot = bf2f(kv.x) * qv.x + bf2f(kv.y) * qv.y + bf2f(kv.z) * qv.z + bf2f(kv.w) * qv.w;
  dot = wred_sum(dot);
  if (lane == 0) sc[(size_t)l * 4096 + trow] = dot * 0.0625f;
}

// ---------- softmax over 4096 per layer ----------
__global__ void softmax_k(const float* __restrict__ sc, float* __restrict__ w) {
  int l = blockIdx.x, t = threadIdx.x;  // 1024 threads
  float4 v = ((const float4*)(sc + (size_t)l * 4096))[t];
  float m = fmaxf(fmaxf(v.x, v.y), fmaxf(v.z, v.w));
  m = wred_max(m);
  __shared__ float red[16];
  __shared__ float red2[16];
  int lane = t & 63, wv = t >> 6;
  if (lane == 0) red[wv] = m;
  __syncthreads();
  float mm = red[0];
#pragma unroll
  for (int i = 1; i < 16; ++i) mm = fmaxf(mm, red[i]);
  float e0 = expf(v.x - mm), e1 = expf(v.y - mm), e2 = expf(v.z - mm), e3 = expf(v.w - mm);
  float s = wred_sum(e0 + e1 + e2 + e3);
  if (lane == 0) red2[wv] = s;
  __syncthreads();
  float tot = 0.f;
#pragma unroll
  for (int i = 0; i < 16; ++i) tot += red2[i];
  float inv = 1.f / tot;
  float4 o = {e0 * inv, e1 * inv, e2 * inv, e3 * inv};
  ((float4*)(w + (size_t)l * 4096))[t] = o;
}

// ---------- ctx: all 6 layers per block, e read once ----------
__global__ void ctx_k(const float* __restrict__ e, const float* __restrict__ w,
                      float* __restrict__ ctx) {
  int c = blockIdx.x, b = blockIdx.y, d = threadIdx.x;
  const float* eb = e + ((size_t)b * 4096 + c * 64) * 256;
  const float* w0 = w + c * 64;
  float a0 = 0.f, a1 = 0.f, a2 = 0.f, a3 = 0.f, a4 = 0.f, a5 = 0.f;
#pragma unroll 4
  for (int i = 0; i < 64; ++i) {
    float ev = eb[(size_t)i * 256 + d];
    a0 += w0[i] * ev;
    a1 += w0[4096 + i] * ev;
    a2 += w0[8192 + i] * ev;
    a3 += w0[12288 + i] * ev;
    a4 += w0[16384 + i] * ev;
    a5 += w0[20480 + i] * ev;
  }
  atomicAdd(&ctx[(0 * 4 + b) * 256 + d], a0);
  atomicAdd(&ctx[(1 * 4 + b) * 256 + d], a1);
  atomicAdd(&ctx[(2 * 4 + b) * 256 + d], a2);
  atomicAdd(&ctx[(3 * 4 + b) * 256 + d], a3);
  atomicAdd(&ctx[(4 * 4 + b) * 256 + d], a4);
  atomicAdd(&ctx[(5 * 4 + b) * 256 + d], a5);
}

// ---------- out_all[l][b] = ctx[l][b] @ Wv[l] ----------
__global__ void proj_k(const float* __restrict__ ctx, const float* __restrict__ Wv,
                       float* __restrict__ outall) {
  int b = blockIdx.x, l = blockIdx.y, t = threadIdx.x;
  const float* cl = ctx + (l * 4 + b) * 256;
  const float* W = Wv + (size_t)l * 65536;
  float acc = 0.f;
#pragma unroll 8
  for (int d = 0; d < 256; ++d) acc += cl[d] * W[d * 256 + t];
  outall[(l * 4 + b) * 256 + t] = acc;
}

// ---------- final LN at last position ----------
__global__ void final_k(const float* __restrict__ e, const float* __restrict__ p0,
                        const float* __restrict__ outall, const float* __restrict__ gout,
                        float* __restrict__ xln) {
  int b = blockIdx.x, t = threadIdx.x;
  float v = e[((size_t)(b * 4096 + 4095)) * 256 + t] + p0[(size_t)4095 * 256 + t];
#pragma unroll
  for (int l = 0; l < 6; ++l) v += outall[(l * 4 + b) * 256 + t];
  __shared__ float s4[4];
  float mean = bsum256(v, s4) * (1.f / 256.f);
  float d = v - mean;
  float var = bsum256(d * d, s4) * (1.f / 256.f);
  xln[b * 256 + t] = d * rsqrtf(var + LN_EPS) * gout[t];
}

// ---------- logits ----------
__global__ void logits_k(const float* __restrict__ wte, const float* __restrict__ ge,
                         const float* __restrict__ xln, float* __restrict__ out) {
  int wv = threadIdx.x >> 6, lane = threadIdx.x & 63;
  int v = blockIdx.x * 4 + wv;
  float4 x = ((const float4*)(wte + (size_t)v * 256))[lane];
  float mean = wred_sum(x.x + x.y + x.z + x.w) * (1.f / 256.f);
  float4 d = {x.x - mean, x.y - mean, x.z - mean, x.w - mean};
  float var = wred_sum(d.x * d.x + d.y * d.y + d.z * d.z + d.w * d.w) * (1.f / 256.f);
  float r = rsqrtf(var + LN_EPS);
  float4 gv = ((const float4*)ge)[lane];
  float4 ln = {d.x * r * gv.x, d.y * r * gv.y, d.z * r * gv.z, d.w * r * gv.w};
#pragma unroll
  for (int b = 0; b < 4; ++b) {
    float4 xv = ((const float4*)(xln + b * 256))[lane];
    float dot = wred_sum(ln.x * xv.x + ln.y * xv.y + ln.z * xv.z + ln.w * xv.w);
    if (lane == 0) out[b * 32000 + v] = dot;
  }
}

// ---------- workspace layout (float units, 16B aligned) ----------
#define O_P0    ((size_t)0)         // f32 4096*256            = 1048576 fl
#define O_E     ((size_t)1048576)   // f32 16384*256           = 4194304 fl
#define O_P0B   ((size_t)5242880)   // bf16 4096*256           = 524288 fl
#define O_W1T   ((size_t)5767168)   // bf16 1024*256           = 131072 fl
#define O_W2T   ((size_t)5898240)   // bf16 256*1024           = 131072 fl
#define O_WKT   ((size_t)6029312)   // bf16 6*256*256          = 196608 fl
#define O_HB    ((size_t)6225920)   // bf16 4096*1024          = 2097152 fl
#define O_PB    ((size_t)8323072)   // bf16 4096*256           = 524288 fl
#define O_KB    ((size_t)8847360)   // bf16 6*4096*256         = 3145728 fl
#define O_QALL  ((size_t)11993088)  // f32 6*256
#define O_SC    ((size_t)11994624)  // f32 6*4096
#define O_WSM   ((size_t)12019200)  // f32 6*4096
#define O_CTX   ((size_t)12043776)  // f32 6*4*256
#define O_OUTA  ((size_t)12049920)  // f32 6*4*256
#define O_XLN   ((size_t)12056064)  // f32 4*256

extern "C" void kernel_launch(void* const* d_in, const int* in_sizes, int n_in,
                              void* d_out, int out_size, void* d_ws, size_t ws_size,
                              hipStream_t stream) {
  const int*   tokens = (const int*)d_in[0];
  const float* wte    = (const float*)d_in[1];
  const float* wpe    = (const float*)d_in[2];
  const float* g_e    = (const float*)d_in[3];
  const float* g_p    = (const float*)d_in[4];
  const float* g_out  = (const float*)d_in[5];
  const float* ff_w1  = (const float*)d_in[6];
  const float* ff_w2  = (const float*)d_in[7];
  const float* Wq     = (const float*)d_in[8];
  const float* Wk     = (const float*)d_in[9];
  const float* Wv     = (const float*)d_in[10];
  float* out = (float*)d_out;
  float* ws = (float*)d_ws;

  float* p0 = ws + O_P0;
  float* e  = ws + O_E;
  __hip_bfloat16* p0b = (__hip_bfloat16*)(ws + O_P0B);
  __hip_bfloat16* w1T = (__hip_bfloat16*)(ws + O_W1T);
  __hip_bfloat16* w2T = (__hip_bfloat16*)(ws + O_W2T);
  __hip_bfloat16* wkT = (__hip_bfloat16*)(ws + O_WKT);
  __hip_bfloat16* hB  = (__hip_bfloat16*)(ws + O_HB);
  __hip_bfloat16* pB  = (__hip_bfloat16*)(ws + O_PB);
  __hip_bfloat16* kB  = (__hip_bfloat16*)(ws + O_KB);
  float* qall = ws + O_QALL;
  float* sc   = ws + O_SC;
  float* wsm  = ws + O_WSM;
  float* ctx  = ws + O_CTX;
  float* outa = ws + O_OUTA;
  float* xln  = ws + O_XLN;

  // embeddings + LNs
  ln_wpe_k<<<1024, 256, 0, stream>>>(wpe, g_p, p0, p0b);
  ln_e_k<<<4096, 256, 0, stream>>>(wte, tokens, g_e, e);
  // weight transpose-casts
  tcast_k<<<dim3(4, 16, 1), 256, 0, stream>>>(ff_w1, w1T, 256, 1024);
  tcast_k<<<dim3(16, 4, 1), 256, 0, stream>>>(ff_w2, w2T, 1024, 256);
  tcast_k<<<dim3(4, 4, 6), 256, 0, stream>>>(Wk, wkT, 256, 256);
  // MLP1: h = gelu(p0 @ ff_w1)
  mfma_gemm<<<dim3(32, 8, 1), 256, 0, stream>>>(p0b, w1T, hB, nullptr, 4096, 1024, 256, 1);
  // MLP2: p = p0 + h @ ff_w2
  mfma_gemm<<<dim3(32, 2, 1), 256, 0, stream>>>(hB, w2T, pB, p0, 4096, 256, 1024, 2);
  // q at last position (all layers)
  qlast_k<<<6, 256, 0, stream>>>(pB, Wq, qall);
  // k[l] = p @ Wk[l]
  mfma_gemm<<<dim3(32, 2, 6), 256, 0, stream>>>(pB, wkT, kB, nullptr, 4096, 256, 256, 0);
  // scores + softmax
  scores_k<<<dim3(1024, 6), 256, 0, stream>>>(kB, qall, sc);
  softmax_k<<<6, 1024, 0, stream>>>(sc, wsm);
  // ctx
  hipMemsetAsync(ctx, 0, 6 * 4 * 256 * sizeof(float), stream);
  ctx_k<<<dim3(64, 4), 256, 0, stream>>>(e, wsm, ctx);
  // Wv projection
  proj_k<<<dim3(4, 6), 256, 0, stream>>>(ctx, Wv, outa);
  // final LN + logits
  final_k<<<4, 256, 0, stream>>>(e, p0, outa, g_out, xln);
  logits_k<<<8000, 256, 0, stream>>>(wte, g_e, xln, out);
}

// Round 3
// 201.175 us; speedup vs baseline: 2.0626x; 1.1753x over previous
//
#include <hip/hip_runtime.h>
#include <hip/hip_bf16.h>

#define LN_EPS 1e-5f

typedef __attribute__((ext_vector_type(8))) short s8v;
typedef __attribute__((ext_vector_type(4))) float f32x4;

// ---------- helpers ----------
__device__ __forceinline__ float wred_sum(float v) {
#pragma unroll
  for (int o = 32; o > 0; o >>= 1) v += __shfl_xor(v, o, 64);
  return v;
}
__device__ __forceinline__ float wred_max(float v) {
#pragma unroll
  for (int o = 32; o > 0; o >>= 1) v = fmaxf(v, __shfl_xor(v, o, 64));
  return v;
}
__device__ __forceinline__ float bsum256(float v, float* s4) {
  v = wred_sum(v);
  int lane = threadIdx.x & 63, w = threadIdx.x >> 6;
  __syncthreads();
  if (lane == 0) s4[w] = v;
  __syncthreads();
  return s4[0] + s4[1] + s4[2] + s4[3];
}
__device__ __forceinline__ float bf2f(unsigned short u) {
  union { unsigned int i; float f; } c;
  c.i = ((unsigned int)u) << 16;
  return c.f;
}
__device__ __forceinline__ void async_cp16(const __hip_bfloat16* g, __hip_bfloat16* l) {
  __builtin_amdgcn_global_load_lds(
      (const __attribute__((address_space(1))) unsigned int*)g,
      (__attribute__((address_space(3))) unsigned int*)l, 16, 0, 0);
}

// ---------- LN(wpe) -> p0 f32 + p0 bf16 ; block 0 also zeroes ctx ----------
__global__ void ln_wpe_k(const float* __restrict__ wpe, const float* __restrict__ g,
                         float* __restrict__ p0, __hip_bfloat16* __restrict__ p0b,
                         float* __restrict__ ctx) {
  if (blockIdx.x == 0) {
    for (int i = threadIdx.x; i < 6 * 4 * 256; i += 256) ctx[i] = 0.f;
  }
  int w = threadIdx.x >> 6, lane = threadIdx.x & 63;
  int row = blockIdx.x * 4 + w;
  const float4* src = (const float4*)(wpe + (size_t)row * 256);
  float4 v = src[lane];
  float mean = wred_sum(v.x + v.y + v.z + v.w) * (1.f / 256.f);
  float4 d = {v.x - mean, v.y - mean, v.z - mean, v.w - mean};
  float var = wred_sum(d.x * d.x + d.y * d.y + d.z * d.z + d.w * d.w) * (1.f / 256.f);
  float r = rsqrtf(var + LN_EPS);
  float4 gv = ((const float4*)g)[lane];
  float4 o = {d.x * r * gv.x, d.y * r * gv.y, d.z * r * gv.z, d.w * r * gv.w};
  ((float4*)(p0 + (size_t)row * 256))[lane] = o;
  __hip_bfloat16* ob = p0b + (size_t)row * 256 + lane * 4;
  ob[0] = (__hip_bfloat16)o.x; ob[1] = (__hip_bfloat16)o.y;
  ob[2] = (__hip_bfloat16)o.z; ob[3] = (__hip_bfloat16)o.w;
}

// ---------- e = LN(wte[tokens], g_e) f32 ----------
__global__ void ln_e_k(const float* __restrict__ wte, const int* __restrict__ tokens,
                       const float* __restrict__ g, float* __restrict__ e) {
  int w = threadIdx.x >> 6, lane = threadIdx.x & 63;
  int row = blockIdx.x * 4 + w;
  int tok = tokens[row];
  const float4* src = (const float4*)(wte + (size_t)tok * 256);
  float4 v = src[lane];
  float mean = wred_sum(v.x + v.y + v.z + v.w) * (1.f / 256.f);
  float4 d = {v.x - mean, v.y - mean, v.z - mean, v.w - mean};
  float var = wred_sum(d.x * d.x + d.y * d.y + d.z * d.z + d.w * d.w) * (1.f / 256.f);
  float r = rsqrtf(var + LN_EPS);
  float4 gv = ((const float4*)g)[lane];
  float4 o = {d.x * r * gv.x, d.y * r * gv.y, d.z * r * gv.z, d.w * r * gv.w};
  ((float4*)(e + (size_t)row * 256))[lane] = o;
}

// ---------- transpose + cast f32 -> bf16 : out[n*M+m] = in[m*N+n] ----------
__global__ void tcast_k(const float* __restrict__ in, __hip_bfloat16* __restrict__ out,
                        int M, int N) {
  __shared__ float lds[64][65];
  int t = threadIdx.x, x = t & 63, y4 = t >> 6;
  int r0 = blockIdx.x * 64, c0 = blockIdx.y * 64;
  const float* inz = in + (size_t)blockIdx.z * M * N;
  __hip_bfloat16* outz = out + (size_t)blockIdx.z * M * N;
#pragma unroll
  for (int i = 0; i < 16; ++i) {
    int r = y4 * 16 + i;
    lds[r][x] = inz[(size_t)(r0 + r) * N + c0 + x];
  }
  __syncthreads();
#pragma unroll
  for (int i = 0; i < 16; ++i) {
    int a = y4 * 16 + i;
    outz[(size_t)(c0 + a) * M + r0 + x] = (__hip_bfloat16)lds[x][a];
  }
}

// ---------- MFMA GEMM: C(MxN) = A(MxK) @ B, B given as BT(NxK) ----------
// Tile: BM x 64, BK=64, 2x2 waves, wave = (TM*16) x 32, async global->LDS,
// XOR-swizzled chunk layout (16B chunk c of row m stored at chunk c^(m&7)).
// mode 0: none; 1: exact gelu; 2: += res(f32 MxN). blockIdx.z: layer.
template <int TM>
__global__ __launch_bounds__(256) void mfma_gemm(
    const __hip_bfloat16* __restrict__ A, const __hip_bfloat16* __restrict__ BT,
    __hip_bfloat16* __restrict__ Cout, const float* __restrict__ res,
    int M, int N, int K, int mode) {
  constexpr int BM = TM * 32;
  __shared__ __hip_bfloat16 As[BM * 64];
  __shared__ __hip_bfloat16 Bs[64 * 64];
  const int t = threadIdx.x;
  const int lane = t & 63, wave = t >> 6;
  const int wr = wave >> 1, wc = wave & 1;
  const int fr = lane & 15, quad = lane >> 4;
  const int m0 = blockIdx.x * BM, n0 = blockIdx.y * 64;
  const __hip_bfloat16* Bl = BT + (size_t)blockIdx.z * N * K;
  __hip_bfloat16* Cl = Cout + (size_t)blockIdx.z * M * N;

  f32x4 acc[TM][2];
#pragma unroll
  for (int i = 0; i < TM; ++i)
#pragma unroll
    for (int j = 0; j < 2; ++j) acc[i][j] = (f32x4){0.f, 0.f, 0.f, 0.f};

  for (int k0 = 0; k0 < K; k0 += 64) {
    __syncthreads();  // readers of previous tile done
    // stage A: TM wave-loads of 1KB per wave
#pragma unroll
    for (int j = 0; j < TM; ++j) {
      int ld = wave * TM + j;
      int slot = ld * 64 + lane;          // 16B slots
      int m = slot >> 3, c = slot & 7;
      const __hip_bfloat16* g = A + (size_t)(m0 + m) * K + k0 + ((c ^ (m & 7)) << 3);
      async_cp16(g, As + ld * 512);       // HW scatters lane*16B
    }
    // stage B: 2 wave-loads per wave
#pragma unroll
    for (int j = 0; j < 2; ++j) {
      int ld = wave * 2 + j;
      int slot = ld * 64 + lane;
      int n = slot >> 3, c = slot & 7;
      const __hip_bfloat16* g = Bl + (size_t)(n0 + n) * K + k0 + ((c ^ (n & 7)) << 3);
      async_cp16(g, Bs + ld * 512);
    }
    __syncthreads();  // drains vmcnt -> LDS tile ready
#pragma unroll
    for (int h = 0; h < 2; ++h) {
      s8v af[TM], bfv[2];
#pragma unroll
      for (int i = 0; i < TM; ++i) {
        int m = wr * TM * 16 + i * 16 + fr;
        int ch = (h * 4 + quad) ^ (m & 7);
        af[i] = *(const s8v*)(As + m * 64 + ch * 8);
      }
#pragma unroll
      for (int j = 0; j < 2; ++j) {
        int n = wc * 32 + j * 16 + fr;
        int ch = (h * 4 + quad) ^ (n & 7);
        bfv[j] = *(const s8v*)(Bs + n * 64 + ch * 8);
      }
#pragma unroll
      for (int i = 0; i < TM; ++i)
#pragma unroll
        for (int j = 0; j < 2; ++j)
          acc[i][j] = __builtin_amdgcn_mfma_f32_16x16x32_bf16(af[i], bfv[j], acc[i][j], 0, 0, 0);
    }
  }

#pragma unroll
  for (int i = 0; i < TM; ++i) {
#pragma unroll
    for (int j = 0; j < 2; ++j) {
#pragma unroll
      for (int r = 0; r < 4; ++r) {
        int row = m0 + wr * TM * 16 + i * 16 + quad * 4 + r;
        int col = n0 + wc * 32 + j * 16 + fr;
        float v = acc[i][j][r];
        if (mode == 1) v = 0.5f * v * (1.f + erff(v * 0.70710678118654752f));
        if (mode == 2) v += res[(size_t)row * N + col];
        Cl[(size_t)row * N + col] = (__hip_bfloat16)v;
      }
    }
  }
}

// ---------- q at last position (p bf16) ----------
__global__ void qlast_k(const __hip_bfloat16* __restrict__ pB, const float* __restrict__ Wq,
                        float* __restrict__ qall) {
  int l = blockIdx.x, t = threadIdx.x;
  const __hip_bfloat16* plast = pB + (size_t)4095 * 256;
  const float* W = Wq + (size_t)l * 65536;
  float acc = 0.f;
#pragma unroll 8
  for (int d = 0; d < 256; ++d) acc += (float)plast[d] * W[d * 256 + t];
  qall[l * 256 + t] = acc;
}

// ---------- scores: wave per row, k bf16 ----------
__global__ void scores_k(const __hip_bfloat16* __restrict__ kB, const float* __restrict__ qall,
                         float* __restrict__ sc) {
  int w = threadIdx.x >> 6, lane = threadIdx.x & 63;
  int trow = blockIdx.x * 4 + w;
  int l = blockIdx.y;
  const unsigned short* kr = (const unsigned short*)(kB + ((size_t)l * 4096 + trow) * 256);
  ushort4 kv = ((const ushort4*)kr)[lane];
  float4 qv = ((const float4*)(qall + l * 256))[lane];
  float dot = bf2f(kv.x) * qv.x + bf2f(kv.y) * qv.y + bf2f(kv.z) * qv.z + bf2f(kv.w) * qv.w;
  dot = wred_sum(dot);
  if (lane == 0) sc[(size_t)l * 4096 + trow] = dot * 0.0625f;
}

// ---------- softmax over 4096 per layer ----------
__global__ void softmax_k(const float* __restrict__ sc, float* __restrict__ w) {
  int l = blockIdx.x, t = threadIdx.x;  // 1024 threads
  float4 v = ((const float4*)(sc + (size_t)l * 4096))[t];
  float m = fmaxf(fmaxf(v.x, v.y), fmaxf(v.z, v.w));
  m = wred_max(m);
  __shared__ float red[16];
  __shared__ float red2[16];
  int lane = t & 63, wv = t >> 6;
  if (lane == 0) red[wv] = m;
  __syncthreads();
  float mm = red[0];
#pragma unroll
  for (int i = 1; i < 16; ++i) mm = fmaxf(mm, red[i]);
  float e0 = expf(v.x - mm), e1 = expf(v.y - mm), e2 = expf(v.z - mm), e3 = expf(v.w - mm);
  float s = wred_sum(e0 + e1 + e2 + e3);
  if (lane == 0) red2[wv] = s;
  __syncthreads();
  float tot = 0.f;
#pragma unroll
  for (int i = 0; i < 16; ++i) tot += red2[i];
  float inv = 1.f / tot;
  float4 o = {e0 * inv, e1 * inv, e2 * inv, e3 * inv};
  ((float4*)(w + (size_t)l * 4096))[t] = o;
}

// ---------- ctx: all 6 layers per block, e read once ----------
__global__ void ctx_k(const float* __restrict__ e, const float* __restrict__ w,
                      float* __restrict__ ctx) {
  int c = blockIdx.x, b = blockIdx.y, d = threadIdx.x;
  const float* eb = e + ((size_t)b * 4096 + c * 64) * 256;
  const float* w0 = w + c * 64;
  float a0 = 0.f, a1 = 0.f, a2 = 0.f, a3 = 0.f, a4 = 0.f, a5 = 0.f;
#pragma unroll 4
  for (int i = 0; i < 64; ++i) {
    float ev = eb[(size_t)i * 256 + d];
    a0 += w0[i] * ev;
    a1 += w0[4096 + i] * ev;
    a2 += w0[8192 + i] * ev;
    a3 += w0[12288 + i] * ev;
    a4 += w0[16384 + i] * ev;
    a5 += w0[20480 + i] * ev;
  }
  atomicAdd(&ctx[(0 * 4 + b) * 256 + d], a0);
  atomicAdd(&ctx[(1 * 4 + b) * 256 + d], a1);
  atomicAdd(&ctx[(2 * 4 + b) * 256 + d], a2);
  atomicAdd(&ctx[(3 * 4 + b) * 256 + d], a3);
  atomicAdd(&ctx[(4 * 4 + b) * 256 + d], a4);
  atomicAdd(&ctx[(5 * 4 + b) * 256 + d], a5);
}

// ---------- out_all[l][b] = ctx[l][b] @ Wv[l] ----------
__global__ void proj_k(const float* __restrict__ ctx, const float* __restrict__ Wv,
                       float* __restrict__ outall) {
  int b = blockIdx.x, l = blockIdx.y, t = threadIdx.x;
  const float* cl = ctx + (l * 4 + b) * 256;
  const float* W = Wv + (size_t)l * 65536;
  float acc = 0.f;
#pragma unroll 8
  for (int d = 0; d < 256; ++d) acc += cl[d] * W[d * 256 + t];
  outall[(l * 4 + b) * 256 + t] = acc;
}

// ---------- final LN at last position ----------
__global__ void final_k(const float* __restrict__ e, const float* __restrict__ p0,
                        const float* __restrict__ outall, const float* __restrict__ gout,
                        float* __restrict__ xln) {
  int b = blockIdx.x, t = threadIdx.x;
  float v = e[((size_t)(b * 4096 + 4095)) * 256 + t] + p0[(size_t)4095 * 256 + t];
#pragma unroll
  for (int l = 0; l < 6; ++l) v += outall[(l * 4 + b) * 256 + t];
  __shared__ float s4[4];
  float mean = bsum256(v, s4) * (1.f / 256.f);
  float d = v - mean;
  float var = bsum256(d * d, s4) * (1.f / 256.f);
  xln[b * 256 + t] = d * rsqrtf(var + LN_EPS) * gout[t];
}

// ---------- logits ----------
__global__ void logits_k(const float* __restrict__ wte, const float* __restrict__ ge,
                         const float* __restrict__ xln, float* __restrict__ out) {
  int wv = threadIdx.x >> 6, lane = threadIdx.x & 63;
  int v = blockIdx.x * 4 + wv;
  float4 x = ((const float4*)(wte + (size_t)v * 256))[lane];
  float mean = wred_sum(x.x + x.y + x.z + x.w) * (1.f / 256.f);
  float4 d = {x.x - mean, x.y - mean, x.z - mean, x.w - mean};
  float var = wred_sum(d.x * d.x + d.y * d.y + d.z * d.z + d.w * d.w) * (1.f / 256.f);
  float r = rsqrtf(var + LN_EPS);
  float4 gv = ((const float4*)ge)[lane];
  float4 ln = {d.x * r * gv.x, d.y * r * gv.y, d.z * r * gv.z, d.w * r * gv.w};
#pragma unroll
  for (int b = 0; b < 4; ++b) {
    float4 xv = ((const float4*)(xln + b * 256))[lane];
    float dot = wred_sum(ln.x * xv.x + ln.y * xv.y + ln.z * xv.z + ln.w * xv.w);
    if (lane == 0) out[b * 32000 + v] = dot;
  }
}

// ---------- workspace layout (float units, 16B aligned) ----------
#define O_P0    ((size_t)0)         // f32 4096*256
#define O_E     ((size_t)1048576)   // f32 16384*256
#define O_P0B   ((size_t)5242880)   // bf16 4096*256
#define O_W1T   ((size_t)5767168)   // bf16 1024*256
#define O_W2T   ((size_t)5898240)   // bf16 256*1024
#define O_WKT   ((size_t)6029312)   // bf16 6*256*256
#define O_HB    ((size_t)6225920)   // bf16 4096*1024
#define O_PB    ((size_t)8323072)   // bf16 4096*256
#define O_KB    ((size_t)8847360)   // bf16 6*4096*256
#define O_QALL  ((size_t)11993088)  // f32 6*256
#define O_SC    ((size_t)11994624)  // f32 6*4096
#define O_WSM   ((size_t)12019200)  // f32 6*4096
#define O_CTX   ((size_t)12043776)  // f32 6*4*256
#define O_OUTA  ((size_t)12049920)  // f32 6*4*256
#define O_XLN   ((size_t)12056064)  // f32 4*256

extern "C" void kernel_launch(void* const* d_in, const int* in_sizes, int n_in,
                              void* d_out, int out_size, void* d_ws, size_t ws_size,
                              hipStream_t stream) {
  const int*   tokens = (const int*)d_in[0];
  const float* wte    = (const float*)d_in[1];
  const float* wpe    = (const float*)d_in[2];
  const float* g_e    = (const float*)d_in[3];
  const float* g_p    = (const float*)d_in[4];
  const float* g_out  = (const float*)d_in[5];
  const float* ff_w1  = (const float*)d_in[6];
  const float* ff_w2  = (const float*)d_in[7];
  const float* Wq     = (const float*)d_in[8];
  const float* Wk     = (const float*)d_in[9];
  const float* Wv     = (const float*)d_in[10];
  float* out = (float*)d_out;
  float* ws = (float*)d_ws;

  float* p0 = ws + O_P0;
  float* e  = ws + O_E;
  __hip_bfloat16* p0b = (__hip_bfloat16*)(ws + O_P0B);
  __hip_bfloat16* w1T = (__hip_bfloat16*)(ws + O_W1T);
  __hip_bfloat16* w2T = (__hip_bfloat16*)(ws + O_W2T);
  __hip_bfloat16* wkT = (__hip_bfloat16*)(ws + O_WKT);
  __hip_bfloat16* hB  = (__hip_bfloat16*)(ws + O_HB);
  __hip_bfloat16* pB  = (__hip_bfloat16*)(ws + O_PB);
  __hip_bfloat16* kB  = (__hip_bfloat16*)(ws + O_KB);
  float* qall = ws + O_QALL;
  float* sc   = ws + O_SC;
  float* wsm  = ws + O_WSM;
  float* ctx  = ws + O_CTX;
  float* outa = ws + O_OUTA;
  float* xln  = ws + O_XLN;

  // embeddings + LNs (ln_wpe block 0 zeroes ctx)
  ln_wpe_k<<<1024, 256, 0, stream>>>(wpe, g_p, p0, p0b, ctx);
  ln_e_k<<<4096, 256, 0, stream>>>(wte, tokens, g_e, e);
  // weight transpose-casts
  tcast_k<<<dim3(4, 16, 1), 256, 0, stream>>>(ff_w1, w1T, 256, 1024);
  tcast_k<<<dim3(16, 4, 1), 256, 0, stream>>>(ff_w2, w2T, 1024, 256);
  tcast_k<<<dim3(4, 4, 6), 256, 0, stream>>>(Wk, wkT, 256, 256);
  // MLP1: h = gelu(p0 @ ff_w1)  [4096x1024x256] 128x64 tiles -> 512 blocks
  mfma_gemm<4><<<dim3(32, 16, 1), 256, 0, stream>>>(p0b, w1T, hB, nullptr, 4096, 1024, 256, 1);
  // MLP2: p = p0 + h @ ff_w2    [4096x256x1024] 64x64 tiles -> 256 blocks
  mfma_gemm<2><<<dim3(64, 4, 1), 256, 0, stream>>>(hB, w2T, pB, p0, 4096, 256, 1024, 2);
  // q at last position (all layers)
  qlast_k<<<6, 256, 0, stream>>>(pB, Wq, qall);
  // k[l] = p @ Wk[l]            [4096x256x256]x6 128x64 tiles -> 768 blocks
  mfma_gemm<4><<<dim3(32, 4, 6), 256, 0, stream>>>(pB, wkT, kB, nullptr, 4096, 256, 256, 0);
  // scores + softmax
  scores_k<<<dim3(1024, 6), 256, 0, stream>>>(kB, qall, sc);
  softmax_k<<<6, 1024, 0, stream>>>(sc, wsm);
  // ctx (pre-zeroed by ln_wpe_k)
  ctx_k<<<dim3(64, 4), 256, 0, stream>>>(e, wsm, ctx);
  // Wv projection
  proj_k<<<dim3(4, 6), 256, 0, stream>>>(ctx, Wv, outa);
  // final LN + logits
  final_k<<<4, 256, 0, stream>>>(e, p0, outa, g_out, xln);
  logits_k<<<8000, 256, 0, stream>>>(wte, g_e, xln, out);
}